// Round 2
// baseline (9713.992 us; speedup 1.0000x reference)
//
#include <hip/hip_runtime.h>

// DecoderModule: B=64, T=128, S=512, E=256, H=512, 2H=1024, GRU_IN=1280
// I/O dtype: float32 (per reference). Internal GEMMs: bf16 MFMA.

#define LDSS 40  // padded LDS row stride in shorts (80B = 5*16B: 16B-aligned)

typedef short bf16x8 __attribute__((ext_vector_type(8)));
typedef float f32x4 __attribute__((ext_vector_type(4)));

__device__ inline ushort f2b(float f) {
    unsigned int u = __float_as_uint(f);
    unsigned int r = (u + 0x7FFFu + ((u >> 16) & 1u)) >> 16;
    return (ushort)r;
}
__device__ inline float b2f(ushort u) {
    return __uint_as_float(((unsigned int)u) << 16);
}
__device__ inline float fast_tanh(float x) {
    x = fminf(fmaxf(x, -15.f), 15.f);
    float ex = __expf(2.f * x);
    return (ex - 1.f) / (ex + 1.f);
}

// fp32 -> bf16 bulk convert (n4 = count/4)
__global__ void f2b4_kernel(const float4* __restrict__ in, ushort4* __restrict__ out, int n4) {
    int i = blockIdx.x * blockDim.x + threadIdx.x;
    int stride = gridDim.x * blockDim.x;
    for (; i < n4; i += stride) {
        float4 v = in[i];
        ushort4 o;
        o.x = f2b(v.x); o.y = f2b(v.y); o.z = f2b(v.z); o.w = f2b(v.w);
        out[i] = o;
    }
}

// ---------------------------------------------------------------------------
// 64x64 MFMA bf16 NT-GEMM tile: C[m,n] = sum_k A[m,k]*B[n,k]. B always bf16
// row-major [N,K]; A either bf16 or fp32 row-major [M,K] (converted during
// LDS staging). fp32 accumulate; C written fp32 (Cf) or bf16 (Cb).
// 256 thr = 4 waves; wave w owns m-strip [w*16,w*16+16) x 64 n.
// Layouts (gfx950, learn_hip-verified): A[m=lane&15][k=(lane>>4)*8+j],
// B[n=lane&15][k=(lane>>4)*8+j], D[row=(lane>>4)*4+reg][col=lane&15].
// ---------------------------------------------------------------------------
template <bool AF32>
__device__ inline void gemm64x64(const void* __restrict__ Av,
                                 const ushort* __restrict__ B,
                                 ushort* As, ushort* Bs,
                                 int lda, int ldb, int K,
                                 float* Cf, ushort* Cb, long ldc,
                                 long m0, long n0)
{
    const int tid  = threadIdx.x;
    const int wave = tid >> 6;
    const int lane = tid & 63;
    const int row  = tid >> 2;         // 0..63 cooperative-load row
    const int kcol = (tid & 3) * 8;    // 0,8,16,24
    const int lrow = lane & 15;
    const int quad = lane >> 4;

    f32x4 acc[4];
#pragma unroll
    for (int i = 0; i < 4; i++) acc[i] = f32x4{0.f, 0.f, 0.f, 0.f};

    const ushort* Ab  = (const ushort*)Av + (m0 + row) * (long)lda + kcol;
    const float*  Afp = (const float*)Av + (m0 + row) * (long)lda + kcol;
    const ushort* Bp  = B + (n0 + row) * (long)ldb + kcol;
    ushort* AsW = As + row * LDSS + kcol;
    ushort* BsW = Bs + row * LDSS + kcol;
    const ushort* AsR = As + (wave * 16 + lrow) * LDSS + quad * 8;
    const ushort* BsR = Bs + lrow * LDSS + quad * 8;

    for (int k0 = 0; k0 < K; k0 += 32) {
        uint4 av;
        if (AF32) {
            float4 f0 = *(const float4*)(Afp + k0);
            float4 f1 = *(const float4*)(Afp + k0 + 4);
            av.x = (uint)f2b(f0.x) | ((uint)f2b(f0.y) << 16);
            av.y = (uint)f2b(f0.z) | ((uint)f2b(f0.w) << 16);
            av.z = (uint)f2b(f1.x) | ((uint)f2b(f1.y) << 16);
            av.w = (uint)f2b(f1.z) | ((uint)f2b(f1.w) << 16);
        } else {
            av = *(const uint4*)(Ab + k0);
        }
        uint4 bv = *(const uint4*)(Bp + k0);
        __syncthreads();              // prev iter's LDS reads done
        *(uint4*)AsW = av;
        *(uint4*)BsW = bv;
        __syncthreads();
        bf16x8 af = *(const bf16x8*)AsR;
#pragma unroll
        for (int nf = 0; nf < 4; nf++) {
            bf16x8 bfv = *(const bf16x8*)(BsR + nf * 16 * LDSS);
            acc[nf] = __builtin_amdgcn_mfma_f32_16x16x32_bf16(af, bfv, acc[nf], 0, 0, 0);
        }
    }

#pragma unroll
    for (int nf = 0; nf < 4; nf++) {
#pragma unroll
        for (int r = 0; r < 4; r++) {
            long m = m0 + wave * 16 + quad * 4 + r;
            long n = n0 + nf * 16 + lrow;
            float v = acc[nf][r];
            if (Cf) Cf[m * ldc + n] = v;
            else    Cb[m * ldc + n] = f2b(v);
        }
    }
}

template <bool AF32>
__global__ void gemm_nt(const void* __restrict__ A, const ushort* __restrict__ B,
                        float* Cf, ushort* Cb,
                        int lda, int ldb, long ldc, int K, int nTilesN)
{
    __shared__ ushort As[64 * LDSS];
    __shared__ ushort Bs[64 * LDSS];
    long m0 = (long)(blockIdx.x / nTilesN) * 64;
    long n0 = (long)(blockIdx.x % nTilesN) * 64;
    gemm64x64<AF32>(A, B, As, Bs, lda, ldb, K, Cf, Cb, ldc, m0, n0);
}

// Phase A of step t: pre_out(t-1) [blocks 0..7], q(t) [8..15], gh(t) [16..39].
__global__ void stepA_kernel(const ushort* __restrict__ h_b,
                             const ushort* __restrict__ cat2,
                             const ushort* __restrict__ Wq,
                             const ushort* __restrict__ Whh,
                             const ushort* __restrict__ Wpre,
                             float* q, float* gh, float* pre_out, int t)
{
    __shared__ ushort As[64 * LDSS];
    __shared__ ushort Bs[64 * LDSS];
    int bid = blockIdx.x;
    const ushort* A; const ushort* B;
    float* Cf; int lda, ldb, K; long ldc, n0;
    if (bid < 8) {
        if (t == 0) return;               // no pre output before step 0
        A = cat2; lda = 1792; B = Wpre; ldb = 1792; K = 1792;
        Cf = pre_out + (long)(t - 1) * 512; ldc = 65536; n0 = (long)bid * 64;
    } else if (bid < 16) {
        A = h_b; lda = 512; B = Wq; ldb = 512; K = 512;
        Cf = q; ldc = 512; n0 = (long)(bid - 8) * 64;
    } else {
        A = h_b; lda = 512; B = Whh; ldb = 512; K = 512;
        Cf = gh; ldc = 1536; n0 = (long)(bid - 16) * 64;
    }
    gemm64x64<false>(A, B, As, Bs, lda, ldb, K, Cf, nullptr, ldc, 0, n0);
}

// Energies: one wave per (b,s). e[b,s] = sum_h tanh(q[b,h]+pk[b,s,h])*wE[h]
__global__ void e_kernel(const ushort* __restrict__ pk, const float* __restrict__ q,
                         const float* __restrict__ wE, const int* __restrict__ mask,
                         float* __restrict__ e)
{
    int wid  = (blockIdx.x * blockDim.x + threadIdx.x) >> 6;  // 0..32767
    int lane = threadIdx.x & 63;
    int b = wid >> 9;
    int s = wid & 511;
    const ushort* pkp = pk + ((long)(b * 512 + s) << 9);
    const float*  qp  = q + ((long)b << 9);
    float acc = 0.f;
#pragma unroll
    for (int j = 0; j < 8; j++) {
        int hh = lane + (j << 6);
        acc += fast_tanh(qp[hh] + b2f(pkp[hh])) * wE[hh];
    }
#pragma unroll
    for (int off = 32; off; off >>= 1) acc += __shfl_xor(acc, off);
    if (lane == 0) {
        int i = (b << 9) + s;
        e[i] = (mask[i] != 0) ? acc : -1e9f;
    }
}

// Softmax (no max-pass: |e| <= sum|wE| ~ 8) + context + x_t staging.
// grid = B*4 blocks of 256; block (b,c) computes ctx[b, c*256..+255].
__global__ void sc_kernel(const float* __restrict__ e,
                          const float* __restrict__ encf, const ushort* __restrict__ encb,
                          int useb, const float* __restrict__ trg,
                          ushort* __restrict__ xcat, ushort* __restrict__ cat2, int t)
{
    __shared__ float alpha[512];
    __shared__ float red[256];
    int b = blockIdx.x >> 2;
    int c = blockIdx.x & 3;
    int tid = threadIdx.x;
    float p0 = __expf(e[(b << 9) + tid]);         // masked -1e9 -> 0
    float p1 = __expf(e[(b << 9) + 256 + tid]);
    alpha[tid] = p0;
    alpha[tid + 256] = p1;
    red[tid] = p0 + p1;
    __syncthreads();
    for (int off = 128; off; off >>= 1) {
        if (tid < off) red[tid] += red[tid + off];
        __syncthreads();
    }
    float inv = 1.f / red[0];
    int d = (c << 8) + tid;
    float a0 = 0.f, a1 = 0.f, a2 = 0.f, a3 = 0.f;
    if (useb) {
        const ushort* encp = encb + ((long)b << 19) + d;
        for (int s = 0; s < 512; s += 4) {
            a0 += alpha[s]     * b2f(encp[(long)s << 10]);
            a1 += alpha[s + 1] * b2f(encp[(long)(s + 1) << 10]);
            a2 += alpha[s + 2] * b2f(encp[(long)(s + 2) << 10]);
            a3 += alpha[s + 3] * b2f(encp[(long)(s + 3) << 10]);
        }
    } else {
        const float* encp = encf + ((long)b << 19) + d;
        for (int s = 0; s < 512; s += 4) {
            a0 += alpha[s]     * encp[(long)s << 10];
            a1 += alpha[s + 1] * encp[(long)(s + 1) << 10];
            a2 += alpha[s + 2] * encp[(long)(s + 2) << 10];
            a3 += alpha[s + 3] * encp[(long)(s + 3) << 10];
        }
    }
    float ctx = ((a0 + a1) + (a2 + a3)) * inv;
    ushort cb = f2b(ctx);
    xcat[b * 1280 + 256 + d] = cb;
    cat2[b * 1792 + 768 + d] = cb;
    if (c == 0) {  // stage x_t
        ushort xv = f2b(trg[((long)b * 128 + t) * 256 + tid]);
        xcat[b * 1280 + tid] = xv;
        cat2[b * 1792 + tid] = xv;
    }
}

// GRU gate math + state update + decoder_states (fp32) output.
__global__ void gates_kernel(const float* __restrict__ gx, const float* __restrict__ gh,
                             const float* __restrict__ bih, const float* __restrict__ bhh,
                             float* __restrict__ h, ushort* __restrict__ h_b,
                             ushort* __restrict__ cat2, float* __restrict__ d_states, int t)
{
    int idx = blockIdx.x * blockDim.x + threadIdx.x;  // 0..32767
    int b = idx >> 9, j = idx & 511;
    const float* gxp = gx + b * 1536;
    const float* ghp = gh + b * 1536;
    float rx = gxp[j]        + bih[j];
    float zx = gxp[j + 512]  + bih[j + 512];
    float nx = gxp[j + 1024] + bih[j + 1024];
    float rh = ghp[j]        + bhh[j];
    float zh = ghp[j + 512]  + bhh[j + 512];
    float nh = ghp[j + 1024] + bhh[j + 1024];
    float r = 1.f / (1.f + __expf(-(rx + rh)));
    float z = 1.f / (1.f + __expf(-(zx + zh)));
    float n = fast_tanh(nx + r * nh);
    float hn = (1.f - z) * n + z * h[idx];
    h[idx] = hn;
    h_b[idx] = f2b(hn);
    cat2[b * 1792 + 256 + j] = f2b(hn);
    d_states[((long)b * 128 + t) * 512 + j] = hn;
}

__global__ void btanh_kernel(const float* __restrict__ tmp, const float* __restrict__ bbr,
                             float* __restrict__ h, ushort* __restrict__ h_b)
{
    int idx = blockIdx.x * blockDim.x + threadIdx.x;  // 0..32767
    int j = idx & 511;
    float v = fast_tanh(tmp[idx] + bbr[j]);
    h[idx] = v;
    h_b[idx] = f2b(v);
}

__global__ void hid_kernel(const float* __restrict__ h, float* __restrict__ out)
{
    int idx = blockIdx.x * blockDim.x + threadIdx.x;
    out[idx] = h[idx];
}

extern "C" void kernel_launch(void* const* d_in, const int* in_sizes, int n_in,
                              void* d_out, int out_size, void* d_ws, size_t ws_size,
                              hipStream_t stream)
{
    (void)in_sizes; (void)n_in; (void)out_size;
    const float* trg  = (const float*)d_in[0];   // [64,128,256]
    const float* enc  = (const float*)d_in[1];   // [64,512,1024]
    const float* encF = (const float*)d_in[2];   // [1,64,1024]
    const int*   mask = (const int*)d_in[3];     // [64,1,512]
    const float* Wkey = (const float*)d_in[4];   // [512,1024]
    const float* Wq   = (const float*)d_in[5];   // [512,512]
    const float* wE   = (const float*)d_in[6];   // [512]
    const float* Wbr  = (const float*)d_in[7];   // [512,1024]
    const float* bbr  = (const float*)d_in[8];   // [512]
    const float* Wih  = (const float*)d_in[9];   // [1536,1280]
    const float* Whh  = (const float*)d_in[10];  // [1536,512]
    const float* bih  = (const float*)d_in[11];  // [1536]
    const float* bhh  = (const float*)d_in[12];  // [1536]
    const float* Wpre = (const float*)d_in[13];  // [512,1792]

    char* p = (char*)d_ws;
    auto alloc = [&](size_t bytes) { void* r = (void*)p; p += (bytes + 255) & ~(size_t)255; return r; };
    ushort* pk     = (ushort*)alloc(16777216ul * 2);  // proj_key bf16 [64*512,512]
    ushort* Wkey_b = (ushort*)alloc(524288ul * 2);
    ushort* Wq_b   = (ushort*)alloc(262144ul * 2);
    ushort* Wbr_b  = (ushort*)alloc(524288ul * 2);
    ushort* Wih_b  = (ushort*)alloc(1966080ul * 2);
    ushort* Whh_b  = (ushort*)alloc(786432ul * 2);
    ushort* Wpre_b = (ushort*)alloc(917504ul * 2);
    float*  h    = (float*)alloc(32768ul * 4);
    ushort* h_b  = (ushort*)alloc(32768ul * 2);
    float*  q    = (float*)alloc(32768ul * 4);
    float*  gh   = (float*)alloc(98304ul * 4);
    float*  gx   = (float*)alloc(98304ul * 4);
    float*  e    = (float*)alloc(32768ul * 4);
    ushort* xcat = (ushort*)alloc(81920ul * 2);
    ushort* cat2 = (ushort*)alloc(114688ul * 2);
    size_t used = (size_t)(p - (char*)d_ws);
    // optional bf16 copy of enc_hidden (67.1 MB) if workspace allows
    int useb = (used + 33554432ul * 2 <= ws_size) ? 1 : 0;
    ushort* enc_b = useb ? (ushort*)alloc(33554432ul * 2) : nullptr;

    float* out_states = (float*)d_out;                 // [64,128,512]
    float* out_hidden = out_states + 64l * 128 * 512;  // [1,64,512]
    float* out_pre    = out_hidden + 64l * 512;        // [64,128,512]

    // weight conversions (bf16)
    f2b4_kernel<<<512, 256, 0, stream>>>((const float4*)Wkey, (ushort4*)Wkey_b, 131072);
    f2b4_kernel<<<256, 256, 0, stream>>>((const float4*)Wq,   (ushort4*)Wq_b,   65536);
    f2b4_kernel<<<512, 256, 0, stream>>>((const float4*)Wbr,  (ushort4*)Wbr_b,  131072);
    f2b4_kernel<<<1920, 256, 0, stream>>>((const float4*)Wih, (ushort4*)Wih_b,  491520);
    f2b4_kernel<<<768, 256, 0, stream>>>((const float4*)Whh,  (ushort4*)Whh_b,  196608);
    f2b4_kernel<<<896, 256, 0, stream>>>((const float4*)Wpre, (ushort4*)Wpre_b, 229376);

    // proj_key = enc_hidden @ W_key^T  (M=32768,N=512,K=1024) -> bf16
    if (useb) {
        f2b4_kernel<<<8192, 256, 0, stream>>>((const float4*)enc, (ushort4*)enc_b, 8388608);
        gemm_nt<false><<<4096, 256, 0, stream>>>(enc_b, Wkey_b, nullptr, pk, 1024, 1024, 512, 1024, 8);
    } else {
        gemm_nt<true><<<4096, 256, 0, stream>>>(enc, Wkey_b, nullptr, pk, 1024, 1024, 512, 1024, 8);
    }
    // bridge: h0 = tanh(enc_final @ W_bridge^T + b)
    gemm_nt<true><<<8, 256, 0, stream>>>(encF, Wbr_b, q, nullptr, 1024, 1024, 512, 1024, 8);
    btanh_kernel<<<128, 256, 0, stream>>>(q, bbr, h, h_b);

    for (int t = 0; t < 128; t++) {
        stepA_kernel<<<40, 256, 0, stream>>>(h_b, cat2, Wq_b, Whh_b, Wpre_b, q, gh, out_pre, t);
        e_kernel<<<8192, 256, 0, stream>>>(pk, q, wE, mask, e);
        sc_kernel<<<256, 256, 0, stream>>>(e, enc, enc_b, useb, trg, xcat, cat2, t);
        gemm_nt<false><<<24, 256, 0, stream>>>(xcat, Wih_b, gx, nullptr, 1280, 1280, 1536, 1280, 24);
        gates_kernel<<<128, 256, 0, stream>>>(gx, gh, bih, bhh, h, h_b, cat2, out_states, t);
    }
    // final pre-output (t=127) and final hidden
    gemm_nt<false><<<8, 256, 0, stream>>>(cat2, Wpre_b, out_pre + 127l * 512, nullptr,
                                          1792, 1792, 65536, 1792, 8);
    hid_kernel<<<128, 256, 0, stream>>>(h, out_hidden);
}

// Round 3
// 6006.362 us; speedup vs baseline: 1.6173x; 1.6173x over previous
//
#include <hip/hip_runtime.h>

// DecoderModule: B=64, T=128, S=512, E=256, H=512, 2H=1024, GRU_IN=1280
// I/O fp32; internal GEMMs bf16 MFMA; K-split GEMMs accumulate via fp32 atomics.

#define LDSS 40  // padded LDS row stride in shorts (80B = 5*16B)

typedef short bf16x8 __attribute__((ext_vector_type(8)));
typedef float f32x4 __attribute__((ext_vector_type(4)));

__device__ inline ushort f2b(float f) {
    unsigned int u = __float_as_uint(f);
    return (ushort)((u + 0x7FFFu + ((u >> 16) & 1u)) >> 16);
}
__device__ inline float b2f(ushort u) {
    return __uint_as_float(((unsigned int)u) << 16);
}
__device__ inline float fast_tanh(float x) {
    x = fminf(fmaxf(x, -15.f), 15.f);
    float ex = __expf(2.f * x);
    return (ex - 1.f) / (ex + 1.f);
}

__global__ void f2b4_kernel(const float4* __restrict__ in, ushort4* __restrict__ out, int n4) {
    int i = blockIdx.x * blockDim.x + threadIdx.x;
    int stride = gridDim.x * blockDim.x;
    for (; i < n4; i += stride) {
        float4 v = in[i];
        ushort4 o;
        o.x = f2b(v.x); o.y = f2b(v.y); o.z = f2b(v.z); o.w = f2b(v.w);
        out[i] = o;
    }
}

// ---------------------------------------------------------------------------
// 64x64 MFMA bf16 NT-GEMM tile over K range [kbeg,kend):
// C[m,n] (+)= sum_k A[m,k]*B[n,k]. B bf16 [N,K]; A bf16 or fp32 [M,K].
// ATOMIC: atomicAdd into fp32 C (K-split). Else plain store fp32/bf16.
// Layouts (gfx950 verified): A[m=lane&15][k=(lane>>4)*8+j], B same,
// D[row=(lane>>4)*4+reg][col=lane&15].
// ---------------------------------------------------------------------------
template <bool AF32, bool ATOMIC>
__device__ inline void gemm64x64(const void* __restrict__ Av,
                                 const ushort* __restrict__ B,
                                 ushort* As, ushort* Bs,
                                 int lda, int ldb, int kbeg, int kend,
                                 float* Cf, ushort* Cb, long ldc,
                                 long m0, long n0)
{
    const int tid  = threadIdx.x;
    const int wave = tid >> 6;
    const int lane = tid & 63;
    const int row  = tid >> 2;
    const int kcol = (tid & 3) * 8;
    const int lrow = lane & 15;
    const int quad = lane >> 4;

    f32x4 acc[4];
#pragma unroll
    for (int i = 0; i < 4; i++) acc[i] = f32x4{0.f, 0.f, 0.f, 0.f};

    const ushort* Ab  = (const ushort*)Av + (m0 + row) * (long)lda + kcol;
    const float*  Afp = (const float*)Av + (m0 + row) * (long)lda + kcol;
    const ushort* Bp  = B + (n0 + row) * (long)ldb + kcol;
    ushort* AsW = As + row * LDSS + kcol;
    ushort* BsW = Bs + row * LDSS + kcol;
    const ushort* AsR = As + (wave * 16 + lrow) * LDSS + quad * 8;
    const ushort* BsR = Bs + lrow * LDSS + quad * 8;

    for (int k0 = kbeg; k0 < kend; k0 += 32) {
        uint4 av;
        if (AF32) {
            float4 f0 = *(const float4*)(Afp + k0);
            float4 f1 = *(const float4*)(Afp + k0 + 4);
            av.x = (uint)f2b(f0.x) | ((uint)f2b(f0.y) << 16);
            av.y = (uint)f2b(f0.z) | ((uint)f2b(f0.w) << 16);
            av.z = (uint)f2b(f1.x) | ((uint)f2b(f1.y) << 16);
            av.w = (uint)f2b(f1.z) | ((uint)f2b(f1.w) << 16);
        } else {
            av = *(const uint4*)(Ab + k0);
        }
        uint4 bv = *(const uint4*)(Bp + k0);
        __syncthreads();
        *(uint4*)AsW = av;
        *(uint4*)BsW = bv;
        __syncthreads();
        bf16x8 af = *(const bf16x8*)AsR;
#pragma unroll
        for (int nf = 0; nf < 4; nf++) {
            bf16x8 bfv = *(const bf16x8*)(BsR + nf * 16 * LDSS);
            acc[nf] = __builtin_amdgcn_mfma_f32_16x16x32_bf16(af, bfv, acc[nf], 0, 0, 0);
        }
    }

#pragma unroll
    for (int nf = 0; nf < 4; nf++) {
#pragma unroll
        for (int r = 0; r < 4; r++) {
            long m = m0 + wave * 16 + quad * 4 + r;
            long n = n0 + nf * 16 + lrow;
            float v = acc[nf][r];
            if (ATOMIC)      atomicAdd(&Cf[m * ldc + n], v);
            else if (Cf)     Cf[m * ldc + n] = v;
            else             Cb[m * ldc + n] = f2b(v);
        }
    }
}

template <bool AF32>
__global__ void gemm_nt(const void* __restrict__ A, const ushort* __restrict__ B,
                        float* Cf, ushort* Cb,
                        int lda, int ldb, long ldc, int K, int nTilesN)
{
    __shared__ ushort As[64 * LDSS];
    __shared__ ushort Bs[64 * LDSS];
    long m0 = (long)(blockIdx.x / nTilesN) * 64;
    long n0 = (long)(blockIdx.x % nTilesN) * 64;
    gemm64x64<AF32, false>(A, B, As, Bs, lda, ldb, 0, K, Cf, Cb, ldc, m0, n0);
}

// Step phase A (96 blocks): pre(t-1) [0..31], q(t) [32..47], gh(t) [48..95].
// All K-split, atomicAdd into zero-initialized fp32 buffers.
__global__ void stepA_kernel(const ushort* __restrict__ h_b,
                             const ushort* __restrict__ cat2,
                             const ushort* __restrict__ Wq,
                             const ushort* __restrict__ Whh,
                             const ushort* __restrict__ Wpre,
                             float* q, float* gh, float* pre_out, int t)
{
    __shared__ ushort As[64 * LDSS];
    __shared__ ushort Bs[64 * LDSS];
    int bid = blockIdx.x;
    if (bid < 32) {
        if (t == 0) return;
        int kc = bid >> 3, nt = bid & 7;
        gemm64x64<false, true>(cat2, Wpre, As, Bs, 1792, 1792, kc * 448, kc * 448 + 448,
                               pre_out + (long)(t - 1) * 512, nullptr, 65536, 0, (long)nt * 64);
    } else if (bid < 48) {
        int b2 = bid - 32, kc = b2 >> 3, nt = b2 & 7;
        gemm64x64<false, true>(h_b, Wq, As, Bs, 512, 512, kc * 256, kc * 256 + 256,
                               q, nullptr, 512, 0, (long)nt * 64);
    } else {
        int b3 = bid - 48, kc = b3 / 24, nt = b3 % 24;
        gemm64x64<false, true>(h_b, Whh, As, Bs, 512, 512, kc * 256, kc * 256 + 256,
                               gh, nullptr, 1536, 0, (long)nt * 64);
    }
}

// gx = [x_t, ctx] @ W_ih^T, K-split 4x320 (96 blocks), atomic into zeroed gx.
__global__ void gx_kernel(const ushort* __restrict__ xcat, const ushort* __restrict__ Wih,
                          float* gx)
{
    __shared__ ushort As[64 * LDSS];
    __shared__ ushort Bs[64 * LDSS];
    int nt = blockIdx.x % 24, kc = blockIdx.x / 24;
    gemm64x64<false, true>(xcat, Wih, As, Bs, 1280, 1280, kc * 320, kc * 320 + 320,
                           gx, nullptr, 1536, 0, (long)nt * 64);
}

// Energies: one wave per (b,s), vectorized bf16x8 load.
__global__ void e_kernel(const ushort* __restrict__ pk, const float* __restrict__ q,
                         const float* __restrict__ wE, const int* __restrict__ mask,
                         float* __restrict__ e)
{
    int wid  = (blockIdx.x * blockDim.x + threadIdx.x) >> 6;  // 0..32767
    int lane = threadIdx.x & 63;
    int b = wid >> 9, s = wid & 511;
    const ushort* pkp = pk + ((long)(b * 512 + s) << 9) + lane * 8;
    const float*  qp  = q + ((long)b << 9) + lane * 8;
    const float*  wp  = wE + lane * 8;
    bf16x8 pv = *(const bf16x8*)pkp;
    float4 q0 = *(const float4*)qp, q1 = *(const float4*)(qp + 4);
    float4 w0 = *(const float4*)wp, w1 = *(const float4*)(wp + 4);
    float acc;
    acc  = fast_tanh(q0.x + b2f((ushort)pv[0])) * w0.x;
    acc += fast_tanh(q0.y + b2f((ushort)pv[1])) * w0.y;
    acc += fast_tanh(q0.z + b2f((ushort)pv[2])) * w0.z;
    acc += fast_tanh(q0.w + b2f((ushort)pv[3])) * w0.w;
    acc += fast_tanh(q1.x + b2f((ushort)pv[4])) * w1.x;
    acc += fast_tanh(q1.y + b2f((ushort)pv[5])) * w1.y;
    acc += fast_tanh(q1.z + b2f((ushort)pv[6])) * w1.z;
    acc += fast_tanh(q1.w + b2f((ushort)pv[7])) * w1.w;
#pragma unroll
    for (int off = 32; off; off >>= 1) acc += __shfl_xor(acc, off);
    if (lane == 0) {
        int i = (b << 9) + s;
        e[i] = (mask[i] != 0) ? acc : -1e9f;
    }
}

// Softmax + context: 1024 blocks (b, d-chunk-of-64). Each block recomputes
// alpha[b,:] (cheap) then reduces 512 s with 4 s-phases x 4-unroll.
__global__ void sc_kernel(const float* __restrict__ e,
                          const float* __restrict__ encf, const ushort* __restrict__ encb,
                          int useb, const float* __restrict__ trg,
                          ushort* __restrict__ xcat, ushort* __restrict__ cat2, int t)
{
    __shared__ float alpha[512];
    __shared__ float red[256];
    __shared__ float part[256];
    int b  = blockIdx.x >> 4;
    int dc = blockIdx.x & 15;
    int tid = threadIdx.x;
    float p0 = __expf(e[(b << 9) + tid]);        // masked -1e9 -> 0
    float p1 = __expf(e[(b << 9) + 256 + tid]);
    alpha[tid] = p0;
    alpha[tid + 256] = p1;
    red[tid] = p0 + p1;
    __syncthreads();
    for (int off = 128; off; off >>= 1) {
        if (tid < off) red[tid] += red[tid + off];
        __syncthreads();
    }
    float inv = 1.f / red[0];
    int dl = tid & 63;     // d lane
    int sr = tid >> 6;     // s phase 0..3
    int d  = (dc << 6) + dl;
    float a0 = 0.f, a1 = 0.f, a2 = 0.f, a3 = 0.f;
    if (useb) {
        const ushort* p = encb + ((long)b << 19) + d;
        for (int s = sr; s < 512; s += 16) {
            a0 += alpha[s]      * b2f(p[(long)s << 10]);
            a1 += alpha[s + 4]  * b2f(p[(long)(s + 4) << 10]);
            a2 += alpha[s + 8]  * b2f(p[(long)(s + 8) << 10]);
            a3 += alpha[s + 12] * b2f(p[(long)(s + 12) << 10]);
        }
    } else {
        const float* p = encf + ((long)b << 19) + d;
        for (int s = sr; s < 512; s += 16) {
            a0 += alpha[s]      * p[(long)s << 10];
            a1 += alpha[s + 4]  * p[(long)(s + 4) << 10];
            a2 += alpha[s + 8]  * p[(long)(s + 8) << 10];
            a3 += alpha[s + 12] * p[(long)(s + 12) << 10];
        }
    }
    part[tid] = ((a0 + a1) + (a2 + a3));
    __syncthreads();
    if (sr == 0) {
        float ctx = (part[dl] + part[64 + dl] + part[128 + dl] + part[192 + dl]) * inv;
        ushort cb = f2b(ctx);
        xcat[b * 1280 + 256 + d] = cb;
        cat2[b * 1792 + 768 + d] = cb;
    } else if (sr == 1 && dc < 4) {   // stage x_t (256 wide per b)
        ushort xv = f2b(trg[((long)b * 128 + t) * 256 + (dc << 6) + dl]);
        xcat[b * 1280 + (dc << 6) + dl] = xv;
        cat2[b * 1792 + (dc << 6) + dl] = xv;
    }
}

// GRU gates + h update + outputs; zero-reinit q/gh/gx and out_pre slice t
// for the NEXT step's atomic accumulation (same thread reads then zeros).
__global__ void gates_kernel(float* __restrict__ gx, float* __restrict__ gh,
                             const float* __restrict__ bih, const float* __restrict__ bhh,
                             float* __restrict__ h, ushort* __restrict__ h_b,
                             ushort* __restrict__ cat2, float* __restrict__ d_states,
                             float* __restrict__ q, float* __restrict__ out_pre, int t)
{
    int idx = blockIdx.x * blockDim.x + threadIdx.x;  // 0..32767
    int b = idx >> 9, j = idx & 511;
    float* gxp = gx + b * 1536;
    float* ghp = gh + b * 1536;
    float rx = gxp[j]        + bih[j];
    float zx = gxp[j + 512]  + bih[j + 512];
    float nx = gxp[j + 1024] + bih[j + 1024];
    float rh = ghp[j]        + bhh[j];
    float zh = ghp[j + 512]  + bhh[j + 512];
    float nh = ghp[j + 1024] + bhh[j + 1024];
    float r = 1.f / (1.f + __expf(-(rx + rh)));
    float z = 1.f / (1.f + __expf(-(zx + zh)));
    float n = fast_tanh(nx + r * nh);
    float hn = (1.f - z) * n + z * h[idx];
    h[idx] = hn;
    h_b[idx] = f2b(hn);
    cat2[b * 1792 + 256 + j] = f2b(hn);
    d_states[((long)b * 128 + t) * 512 + j] = hn;
    // re-zero accumulators for next step
    gxp[j] = 0.f; gxp[j + 512] = 0.f; gxp[j + 1024] = 0.f;
    ghp[j] = 0.f; ghp[j + 512] = 0.f; ghp[j + 1024] = 0.f;
    q[idx] = 0.f;
    out_pre[((long)b * 128 + t) * 512 + j] = 0.f;
}

// bridge tanh + zero-init all atomic accumulators for step 0.
__global__ void btanh_kernel(const float* __restrict__ br, const float* __restrict__ bbr,
                             float* __restrict__ h, ushort* __restrict__ h_b,
                             float* __restrict__ q, float* __restrict__ gh,
                             float* __restrict__ gx)
{
    int idx = blockIdx.x * blockDim.x + threadIdx.x;  // 0..32767
    int b = idx >> 9, j = idx & 511;
    float v = fast_tanh(br[idx] + bbr[j]);
    h[idx] = v;
    h_b[idx] = f2b(v);
    q[idx] = 0.f;
    gh[b * 1536 + j] = 0.f; gh[b * 1536 + j + 512] = 0.f; gh[b * 1536 + j + 1024] = 0.f;
    gx[b * 1536 + j] = 0.f; gx[b * 1536 + j + 512] = 0.f; gx[b * 1536 + j + 1024] = 0.f;
}

__global__ void hid_kernel(const float* __restrict__ h, float* __restrict__ out)
{
    int idx = blockIdx.x * blockDim.x + threadIdx.x;
    out[idx] = h[idx];
}

extern "C" void kernel_launch(void* const* d_in, const int* in_sizes, int n_in,
                              void* d_out, int out_size, void* d_ws, size_t ws_size,
                              hipStream_t stream)
{
    (void)in_sizes; (void)n_in; (void)out_size;
    const float* trg  = (const float*)d_in[0];
    const float* enc  = (const float*)d_in[1];
    const float* encF = (const float*)d_in[2];
    const int*   mask = (const int*)d_in[3];
    const float* Wkey = (const float*)d_in[4];
    const float* Wq   = (const float*)d_in[5];
    const float* wE   = (const float*)d_in[6];
    const float* Wbr  = (const float*)d_in[7];
    const float* bbr  = (const float*)d_in[8];
    const float* Wih  = (const float*)d_in[9];
    const float* Whh  = (const float*)d_in[10];
    const float* bih  = (const float*)d_in[11];
    const float* bhh  = (const float*)d_in[12];
    const float* Wpre = (const float*)d_in[13];

    char* p = (char*)d_ws;
    auto alloc = [&](size_t bytes) { void* r = (void*)p; p += (bytes + 255) & ~(size_t)255; return r; };
    ushort* pk     = (ushort*)alloc(16777216ul * 2);
    ushort* Wkey_b = (ushort*)alloc(524288ul * 2);
    ushort* Wq_b   = (ushort*)alloc(262144ul * 2);
    ushort* Wbr_b  = (ushort*)alloc(524288ul * 2);
    ushort* Wih_b  = (ushort*)alloc(1966080ul * 2);
    ushort* Whh_b  = (ushort*)alloc(786432ul * 2);
    ushort* Wpre_b = (ushort*)alloc(917504ul * 2);
    float*  h    = (float*)alloc(32768ul * 4);
    ushort* h_b  = (ushort*)alloc(32768ul * 2);
    float*  br   = (float*)alloc(32768ul * 4);
    float*  q    = (float*)alloc(32768ul * 4);
    float*  gh   = (float*)alloc(98304ul * 4);
    float*  gx   = (float*)alloc(98304ul * 4);
    float*  e    = (float*)alloc(32768ul * 4);
    ushort* xcat = (ushort*)alloc(81920ul * 2);
    ushort* cat2 = (ushort*)alloc(114688ul * 2);
    size_t used = (size_t)(p - (char*)d_ws);
    int useb = (used + 33554432ul * 2 <= ws_size) ? 1 : 0;
    ushort* enc_b = useb ? (ushort*)alloc(33554432ul * 2) : nullptr;

    float* out_states = (float*)d_out;
    float* out_hidden = out_states + 64l * 128 * 512;
    float* out_pre    = out_hidden + 64l * 512;

    f2b4_kernel<<<512, 256, 0, stream>>>((const float4*)Wkey, (ushort4*)Wkey_b, 131072);
    f2b4_kernel<<<256, 256, 0, stream>>>((const float4*)Wq,   (ushort4*)Wq_b,   65536);
    f2b4_kernel<<<512, 256, 0, stream>>>((const float4*)Wbr,  (ushort4*)Wbr_b,  131072);
    f2b4_kernel<<<1920, 256, 0, stream>>>((const float4*)Wih, (ushort4*)Wih_b,  491520);
    f2b4_kernel<<<768, 256, 0, stream>>>((const float4*)Whh,  (ushort4*)Whh_b,  196608);
    f2b4_kernel<<<896, 256, 0, stream>>>((const float4*)Wpre, (ushort4*)Wpre_b, 229376);

    if (useb) {
        f2b4_kernel<<<8192, 256, 0, stream>>>((const float4*)enc, (ushort4*)enc_b, 8388608);
        gemm_nt<false><<<4096, 256, 0, stream>>>(enc_b, Wkey_b, nullptr, pk, 1024, 1024, 512, 1024, 8);
    } else {
        gemm_nt<true><<<4096, 256, 0, stream>>>(enc, Wkey_b, nullptr, pk, 1024, 1024, 512, 1024, 8);
    }
    gemm_nt<true><<<8, 256, 0, stream>>>(encF, Wbr_b, br, nullptr, 1024, 1024, 512, 1024, 8);
    btanh_kernel<<<128, 256, 0, stream>>>(br, bbr, h, h_b, q, gh, gx);

    for (int t = 0; t < 128; t++) {
        stepA_kernel<<<96, 256, 0, stream>>>(h_b, cat2, Wq_b, Whh_b, Wpre_b, q, gh, out_pre, t);
        e_kernel<<<8192, 256, 0, stream>>>(pk, q, wE, mask, e);
        sc_kernel<<<1024, 256, 0, stream>>>(e, enc, enc_b, useb, trg, xcat, cat2, t);
        gx_kernel<<<96, 256, 0, stream>>>(xcat, Wih_b, gx);
        gates_kernel<<<128, 256, 0, stream>>>(gx, gh, bih, bhh, h, h_b, cat2, out_states,
                                              q, out_pre, t);
    }
    // final pre-output: grid of 32 covers only the pre branch (t=128 -> slice 127)
    stepA_kernel<<<32, 256, 0, stream>>>(h_b, cat2, Wq_b, Whh_b, Wpre_b, q, gh, out_pre, 128);
    hid_kernel<<<128, 256, 0, stream>>>(h, out_hidden);
}